// Round 20
// baseline (86.064 us; speedup 1.0000x reference)
//
#include <hip/hip_runtime.h>
#include <math.h>

// SO(3) convolution, B_IN=16, B_OUT=8, BATCH=32, F_IN=16, F_OUT=32.
// Pipeline v19 (4 launches; v18 base + n-paired kD):
//   A12P: partial 2D DFT (4 slices/block) + prep tail (yhat, wfT, wiTd)
//   A3  : forward Wigner reduce over b; one block per zf
//   kD  : per-(l,m,n-pair) complex GEMM — X panel (depends only on l,m)
//         shared across two n outputs. grid 408 = 204 pairs x 2 z-halves.
//   kE4 : dense inverse Wigner + n-DFT + Hermitian m-DFT; two zg per block.

#define NS 680      // full spectral size
#define NR 372      // restricted (m>=0) spectral size
#define NP 24
#define NW 15
#define SLB 4       // slices per A12 block
#define SCALING 0.14433756729740643f  // 1/sqrt(48)

__device__ __constant__ int c_s0[9] = {0, 1, 10, 35, 84, 165, 286, 455, 680};
__device__ __constant__ int c_o[9]  = {0, 1, 7, 22, 50, 95, 161, 252, 372};
__device__ __constant__ int c_p[9]  = {0, 1, 5, 14, 30, 55, 91, 140, 204};  // sum (l+1)^2

// e^{-2pi i k/32}
__device__ __constant__ float2 TW32[32] = {
    { 1.0000000000f,  0.0000000000f}, { 0.9807852804f, -0.1950903220f},
    { 0.9238795325f, -0.3826834324f}, { 0.8314696123f, -0.5555702330f},
    { 0.7071067812f, -0.7071067812f}, { 0.5555702330f, -0.8314696123f},
    { 0.3826834324f, -0.9238795325f}, { 0.1950903220f, -0.9807852804f},
    { 0.0000000000f, -1.0000000000f}, {-0.1950903220f, -0.9807852804f},
    {-0.3826834324f, -0.9238795325f}, {-0.5555702330f, -0.8314696123f},
    {-0.7071067812f, -0.7071067812f}, {-0.8314696123f, -0.5555702330f},
    {-0.9238795325f, -0.3826834324f}, {-0.9807852804f, -0.1950903220f},
    {-1.0000000000f,  0.0000000000f}, {-0.9807852804f,  0.1950903220f},
    {-0.9238795325f,  0.3826834324f}, {-0.8314696123f,  0.5555702330f},
    {-0.7071067812f,  0.7071067812f}, {-0.5555702330f,  0.8314696123f},
    {-0.3826834324f,  0.9238795325f}, {-0.1950903220f,  0.9807852804f},
    { 0.0000000000f,  1.0000000000f}, { 0.1950903220f,  0.9807852804f},
    { 0.3826834324f,  0.9238795325f}, { 0.5555702330f,  0.8314696123f},
    { 0.7071067812f,  0.7071067812f}, { 0.8314696123f,  0.5555702330f},
    { 0.9238795325f,  0.3826834324f}, { 0.9807852804f,  0.1950903220f}};

// e^{+2pi i k/16}
__device__ __constant__ float2 TW16P[16] = {
    { 1.0000000000f,  0.0000000000f}, { 0.9238795325f,  0.3826834324f},
    { 0.7071067812f,  0.7071067812f}, { 0.3826834324f,  0.9238795325f},
    { 0.0000000000f,  1.0000000000f}, {-0.3826834324f,  0.9238795325f},
    {-0.7071067812f,  0.7071067812f}, {-0.9238795325f,  0.3826834324f},
    {-1.0000000000f,  0.0000000000f}, {-0.9238795325f, -0.3826834324f},
    {-0.7071067812f, -0.7071067812f}, {-0.3826834324f, -0.9238795325f},
    { 0.0000000000f, -1.0000000000f}, { 0.3826834324f, -0.9238795325f},
    { 0.7071067812f, -0.7071067812f}, { 0.9238795325f, -0.3826834324f}};

// ---------------- A12P: partial forward DFT + prep tail ---------------------
// grid 5567 = 4096 (A12) + 1471 (prep), block 256.
__global__ __launch_bounds__(256) void A12P(const float* __restrict__ x,
                                            const float* __restrict__ kern,
                                            const float* __restrict__ fre,
                                            const float* __restrict__ fim,
                                            const float* __restrict__ wf,
                                            const float* __restrict__ wi,
                                            float2* __restrict__ xf2,
                                            float2* __restrict__ yhat,
                                            float* __restrict__ wfT,
                                            float* __restrict__ wiTd) {
    __shared__ __align__(16) float  sx[SLB * 1152];   // [sl][u][v] pad 36; reused as xfb
    __shared__ __align__(16) float2 st[SLB][8][34];   // [sl][n][u] pad 34
    __shared__ float2 tw[32];
    int bid = blockIdx.x;
    int tid = threadIdx.x;
    if (bid >= 4096) {   // ---- prep tail (former kP) ----
        int idx = (bid - 4096) * 256 + tid;
        if (idx < NS * 512) {
            int s = idx >> 9, fg = idx & 511;
            float re = 0.f, im = 0.f;
            for (int p = 0; p < NP; p++) {
                float kv = kern[fg * NP + p];
                re += kv * fre[p * NS + s];
                im += kv * fim[p * NS + s];
            }
            yhat[(size_t)s * 512 + fg] = make_float2(re * SCALING, im * SCALING);
            return;
        }
        int j = idx - NS * 512;
        if (j < NR * 32) {
            int sp = j >> 5, b = j & 31;
            int l = 0;
#pragma unroll
            for (int t = 1; t < 8; t++) if (sp >= c_o[t]) l = t;
            int K = 2 * l + 1, r = sp - c_o[l];
            int m = r / K, jn = r - m * K;
            int sf = c_s0[l] + (m + l) * K + jn;
            wfT[sp * 32 + b] = wf[b * NS + sf];
            return;
        }
        int k = j - NR * 32;
        if (k >= 16384) return;
        int ni = k & 15, mm = (k >> 4) & 7, b8 = (k >> 7) & 7;
        int l = (k >> 10) & 7, bh = k >> 13;
        int nn = ni - 7;
        float v = 0.f;
        if (ni < 15 && mm <= l && nn >= -l && nn <= l) {
            int K = 2 * l + 1;
            v = wi[(bh * 8 + b8) * NS + c_s0[l] + (mm + l) * K + (nn + l)];
        }
        wiTd[k] = v;
        return;
    }
    // ---- A12 body ----
    int blk = bid;
    if (tid < 32) tw[tid] = TW32[tid];
    {
        const float4* xs = (const float4*)(x + (size_t)blk * (SLB * 1024));
#pragma unroll
        for (int q = 0; q < SLB; q++) {
            int idx = q * 256 + tid;
            float4 v4 = xs[idx];
            int sl = idx >> 8, w = idx & 255;
            *(float4*)&sx[sl * 1152 + (w >> 3) * 36 + (w & 7) * 4] = v4;
        }
    }
    __syncthreads();
    {   // step 1 (radix-2 over v)
        int u = tid >> 3, n = tid & 7;
        float sgn = (n & 1) ? -1.f : 1.f;
        float2 t8[8];
#pragma unroll
        for (int c = 0; c < 8; c++) t8[c] = tw[(n * c) & 31];
        float2 fa1 = tw[(8 * n) & 31];
#pragma unroll
        for (int sl = 0; sl < SLB; sl++) {
            const float* row = &sx[sl * 1152 + u * 36];
            float4 x0 = *(float4*)&row[0],  x1 = *(float4*)&row[4];
            float4 x2 = *(float4*)&row[8],  x3 = *(float4*)&row[12];
            float4 x4 = *(float4*)&row[16], x5 = *(float4*)&row[20];
            float4 x6 = *(float4*)&row[24], x7 = *(float4*)&row[28];
            float y0  = fmaf(sgn, x4.x, x0.x), y1  = fmaf(sgn, x4.y, x0.y);
            float y2  = fmaf(sgn, x4.z, x0.z), y3  = fmaf(sgn, x4.w, x0.w);
            float y4  = fmaf(sgn, x5.x, x1.x), y5  = fmaf(sgn, x5.y, x1.y);
            float y6  = fmaf(sgn, x5.z, x1.z), y7  = fmaf(sgn, x5.w, x1.w);
            float y8  = fmaf(sgn, x6.x, x2.x), y9  = fmaf(sgn, x6.y, x2.y);
            float y10 = fmaf(sgn, x6.z, x2.z), y11 = fmaf(sgn, x6.w, x2.w);
            float y12 = fmaf(sgn, x7.x, x3.x), y13 = fmaf(sgn, x7.y, x3.y);
            float y14 = fmaf(sgn, x7.z, x3.z), y15 = fmaf(sgn, x7.w, x3.w);
            float p0r = y0 * t8[0].x + y1 * t8[1].x + y2 * t8[2].x + y3 * t8[3].x
                      + y4 * t8[4].x + y5 * t8[5].x + y6 * t8[6].x + y7 * t8[7].x;
            float p0i = y0 * t8[0].y + y1 * t8[1].y + y2 * t8[2].y + y3 * t8[3].y
                      + y4 * t8[4].y + y5 * t8[5].y + y6 * t8[6].y + y7 * t8[7].y;
            float p1r = y8 * t8[0].x + y9 * t8[1].x + y10 * t8[2].x + y11 * t8[3].x
                      + y12 * t8[4].x + y13 * t8[5].x + y14 * t8[6].x + y15 * t8[7].x;
            float p1i = y8 * t8[0].y + y9 * t8[1].y + y10 * t8[2].y + y11 * t8[3].y
                      + y12 * t8[4].y + y13 * t8[5].y + y14 * t8[6].y + y15 * t8[7].y;
            float re = p0r + fa1.x * p1r - fa1.y * p1i;
            float im = p0i + fa1.x * p1i + fa1.y * p1r;
            st[sl][n][u] = make_float2(re, im);
        }
    }
    __syncthreads();
    float2* xfb = (float2*)sx;       // [sl][120] overlay on dead sx region
    {   // step 2: conj-pair outputs -> LDS
        int sl = tid >> 6, m = (tid >> 3) & 7, jj = tid & 7;
        float2 t8[8], fa[4];
#pragma unroll
        for (int c = 0; c < 8; c++) t8[c] = tw[(m * c) & 31];
        fa[0] = make_float2(1.f, 0.f);
#pragma unroll
        for (int a = 1; a < 4; a++) fa[a] = tw[(8 * m * a) & 31];
        float reP = 0.f, imP = 0.f, reN = 0.f, imN = 0.f;
#pragma unroll
        for (int a = 0; a < 4; a++) {
            const float4* spt = (const float4*)&st[sl][jj][a * 8];
            float4 r0 = spt[0], r1 = spt[1], r2 = spt[2], r3 = spt[3];
            float A = r0.x * t8[0].x + r0.z * t8[1].x + r1.x * t8[2].x + r1.z * t8[3].x
                    + r2.x * t8[4].x + r2.z * t8[5].x + r3.x * t8[6].x + r3.z * t8[7].x;
            float B = r0.y * t8[0].y + r0.w * t8[1].y + r1.y * t8[2].y + r1.w * t8[3].y
                    + r2.y * t8[4].y + r2.w * t8[5].y + r3.y * t8[6].y + r3.w * t8[7].y;
            float C = r0.x * t8[0].y + r0.z * t8[1].y + r1.x * t8[2].y + r1.z * t8[3].y
                    + r2.x * t8[4].y + r2.z * t8[5].y + r3.x * t8[6].y + r3.z * t8[7].y;
            float D = r0.y * t8[0].x + r0.w * t8[1].x + r1.y * t8[2].x + r1.w * t8[3].x
                    + r2.y * t8[4].x + r2.w * t8[5].x + r3.y * t8[6].x + r3.w * t8[7].x;
            float prP = A - B, piP = C + D;
            float prN = A + B, piN = C - D;
            reP += fa[a].x * prP - fa[a].y * piP;
            imP += fa[a].x * piP + fa[a].y * prP;
            reN += fa[a].x * prN - fa[a].y * piN;
            imN += fa[a].x * piN + fa[a].y * prN;
        }
        float2* ob = xfb + sl * 120 + m * 15;
        ob[7 + jj] = make_float2(reP, imP);
        if (jj) ob[7 - jj] = make_float2(reN, imN);
    }
    __syncthreads();
    {   // coalesced flush: 480 float2 = 240 float4
        if (tid < 240) {
            float4* dst = (float4*)(xf2 + (size_t)blk * (SLB * 120));
            dst[tid] = ((float4*)xfb)[tid];
        }
    }
}

// ---------------- A3: forward Wigner reduce over b (one block per zf) -------
__global__ __launch_bounds__(256) void A3(const float2* __restrict__ xf2,
                                          const float* __restrict__ wfT,
                                          float2* __restrict__ xhat) {
    __shared__ __align__(16) float2 sxf[32 * 120];
    int zf = blockIdx.x;
    int tid = threadIdx.x;
    {   // float4 staging of contiguous 30 KB tile
        const float4* src = (const float4*)(xf2 + (size_t)zf * (32 * 120));
        float4* dst = (float4*)sxf;
        for (int t = tid; t < 32 * 60; t += 256) dst[t] = src[t];
    }
    __syncthreads();
#pragma unroll
    for (int q = 0; q < 2; q++) {
        if (q == 1 && tid >= NR - 256) break;      // 372 = 256 + 116
        int sp = tid + q * 256;
        int l = 0;
#pragma unroll
        for (int t = 1; t < 8; t++) if (sp >= c_o[t]) l = t;
        int K = 2 * l + 1, r = sp - c_o[l];
        int m = r / K, jn = r - m * K;
        int cell = m * 15 + (jn - l + 7);
        const float4* wp = (const float4*)(wfT + sp * 32);
        const float2* xp = sxf + cell;
        float re = 0.f, im = 0.f;
#pragma unroll
        for (int qq = 0; qq < 8; qq++) {
            float4 w4 = wp[qq];
            float2 v0 = xp[(qq * 4 + 0) * 120];
            float2 v1 = xp[(qq * 4 + 1) * 120];
            float2 v2 = xp[(qq * 4 + 2) * 120];
            float2 v3 = xp[(qq * 4 + 3) * 120];
            re += w4.x * v0.x + w4.y * v1.x + w4.z * v2.x + w4.w * v3.x;
            im += w4.x * v0.y + w4.y * v1.y + w4.z * v2.y + w4.w * v3.y;
        }
        xhat[(size_t)sp * 512 + zf] = make_float2(re, im);
    }
}

// ---------------- kD: n-paired complex GEMM ---------------------------------
// grid 408 = pair(204) x z-half(2), block 256. Pair (l,m,np): n0=2np (+ n1).
// X panel (l,m) staged once, shared by both n outputs.
__global__ __launch_bounds__(256) void kD(const float2* __restrict__ xhat,
                                          const float2* __restrict__ yhat,
                                          float2* __restrict__ zbufT) {
    __shared__ __align__(16) float2 Xs[4][16][18];       // [kw][f][z-local]
    __shared__ __align__(16) float2 Ys[2][4][16][34];    // [nn][kw][f][g]
    int pb = 203 - (blockIdx.x >> 1);
    int zh = blockIdx.x & 1;
    int l = 0;
#pragma unroll
    for (int t = 1; t < 8; t++) if (pb >= c_p[t]) l = t;
    int r = pb - c_p[l];
    int m = r / (l + 1), np = r - m * (l + 1);
    int K = 2 * l + 1;
    int n0 = 2 * np;
    bool has2 = (n0 + 1) < K;
    int sX0  = c_o[l] + m * K;
    int sY0a = c_s0[l] + n0 * K;
    int sY0b = sY0a + K;
    int spA  = c_o[l] + m * K + n0;      // restricted output index for n0
    int tid = threadIdx.x;
    int zl = tid >> 4;
    int g0 = (tid & 15) * 2;
    float2 a0a = make_float2(0.f, 0.f), a1a = make_float2(0.f, 0.f);
    float2 a0b = make_float2(0.f, 0.f), a1b = make_float2(0.f, 0.f);
    int nchunks = (K + 3) >> 2;
    for (int chunk = 0; chunk < nchunks; ++chunk) {
#pragma unroll
        for (int kw = 0; kw < 4; kw++) {           // X: 256 f2 per kw
            int k = chunk * 4 + kw;
            if (k < K)
                Xs[kw][tid & 15][tid >> 4] =
                    xhat[(size_t)(sX0 + k) * 512 + (zh * 16 + (tid >> 4)) * 16 + (tid & 15)];
        }
#pragma unroll
        for (int it = 0; it < 8; it++) {           // Y nn=0
            int kw = it >> 1;
            int fg = (it & 1) * 256 + tid;
            int k = chunk * 4 + kw;
            if (k < K)
                Ys[0][kw][fg >> 5][fg & 31] = yhat[(size_t)(sY0a + k) * 512 + fg];
        }
        if (has2) {
#pragma unroll
            for (int it = 0; it < 8; it++) {       // Y nn=1
                int kw = it >> 1;
                int fg = (it & 1) * 256 + tid;
                int k = chunk * 4 + kw;
                if (k < K)
                    Ys[1][kw][fg >> 5][fg & 31] = yhat[(size_t)(sY0b + k) * 512 + fg];
            }
        }
        __syncthreads();
        if (has2) {
#pragma unroll
            for (int kw = 0; kw < 4; kw++) {
                int k = chunk * 4 + kw;
                if (k < K) {
#pragma unroll
                    for (int f = 0; f < 16; f++) {
                        float2 xv = Xs[kw][f][zl];
                        float4 ya = *(const float4*)&Ys[0][kw][f][g0];
                        float4 yb = *(const float4*)&Ys[1][kw][f][g0];
                        a0a.x += xv.x * ya.x + xv.y * ya.y;
                        a0a.y += xv.y * ya.x - xv.x * ya.y;
                        a1a.x += xv.x * ya.z + xv.y * ya.w;
                        a1a.y += xv.y * ya.z - xv.x * ya.w;
                        a0b.x += xv.x * yb.x + xv.y * yb.y;
                        a0b.y += xv.y * yb.x - xv.x * yb.y;
                        a1b.x += xv.x * yb.z + xv.y * yb.w;
                        a1b.y += xv.y * yb.z - xv.x * yb.w;
                    }
                }
            }
        } else {
#pragma unroll
            for (int kw = 0; kw < 4; kw++) {
                int k = chunk * 4 + kw;
                if (k < K) {
#pragma unroll
                    for (int f = 0; f < 16; f++) {
                        float2 xv = Xs[kw][f][zl];
                        float4 ya = *(const float4*)&Ys[0][kw][f][g0];
                        a0a.x += xv.x * ya.x + xv.y * ya.y;
                        a0a.y += xv.y * ya.x - xv.x * ya.y;
                        a1a.x += xv.x * ya.z + xv.y * ya.w;
                        a1a.y += xv.y * ya.z - xv.x * ya.w;
                    }
                }
            }
        }
        __syncthreads();
    }
    int z0 = zh * 16 + zl;
    zbufT[(size_t)(z0 * 32 + g0) * NR + spA]     = a0a;
    zbufT[(size_t)(z0 * 32 + g0 + 1) * NR + spA] = a1a;
    if (has2) {
        zbufT[(size_t)(z0 * 32 + g0) * NR + spA + 1]     = a0b;
        zbufT[(size_t)(z0 * 32 + g0 + 1) * NR + spA + 1] = a1b;
    }
}

// ---------------- kE4: inverse Wigner + inverse 2D DFT, TWO zg per block ----
// grid 512, block 256 = (b, mm, vh); weight loads shared across both zg.
__global__ __launch_bounds__(256) void kE4(const float2* __restrict__ zbufT,
                                           const float* __restrict__ wiTd,
                                           const float* __restrict__ bias,
                                           float* __restrict__ out) {
    __shared__ float2 szp[2][384];        // per-zg padded sz
    __shared__ float2 g1[2][16 * 139];    // per-zg bank-safe g1
    __shared__ float2 tw[16];             // e^{+2pi i k/16}
    int zg0 = blockIdx.x * 2;
    int tid = threadIdx.x;
    if (tid < 16) tw[tid] = TW16P[tid];
    if (tid < 8)    { szp[0][tid] = make_float2(0.f, 0.f);
                      szp[1][tid] = make_float2(0.f, 0.f); }
    if (tid >= 252) { szp[0][tid + 128] = make_float2(0.f, 0.f);
                      szp[1][tid + 128] = make_float2(0.f, 0.f); }
    for (int t = tid; t < NR; t += 256) {
        szp[0][8 + t] = zbufT[(size_t)zg0 * NR + t];
        szp[1][8 + t] = zbufT[(size_t)(zg0 + 1) * NR + t];
    }
    __syncthreads();
    {   // phase 1: (b, mm, vh): dense Wigner rows for BOTH zg + half n-DFT
        int b = tid & 15, mm = (tid >> 4) & 7, vh = tid >> 7;  // vh 0..1
        int bh = b >> 3, b8 = b & 7;
        const int co[8] = {0, 1, 7, 22, 50, 95, 161, 252};
        float2 ff0[15], ff1[15];
#pragma unroll
        for (int n = 0; n < 15; n++) {
            ff0[n] = make_float2(0.f, 0.f);
            ff1[n] = make_float2(0.f, 0.f);
        }
#pragma unroll
        for (int l = 0; l < 8; l++) {
            const float4* wl = (const float4*)(wiTd + ((((bh * 8 + l) * 8 + b8) * 8 + mm) << 4));
            float4 w0 = wl[0], w1 = wl[1], w2 = wl[2], w3 = wl[3];
            float wreg[16] = {w0.x, w0.y, w0.z, w0.w, w1.x, w1.y, w1.z, w1.w,
                              w2.x, w2.y, w2.z, w2.w, w3.x, w3.y, w3.z, w3.w};
            int sp = 1 + co[l] + mm * (2 * l + 1) + l;   // szp index for ni=0
#pragma unroll
            for (int ni = 0; ni < 15; ni++) {
                float w = wreg[ni];
                float2 v0 = szp[0][sp + ni];
                float2 v1 = szp[1][sp + ni];
                ff0[ni].x += w * v0.x; ff0[ni].y += w * v0.y;
                ff1[ni].x += w * v1.x; ff1[ni].y += w * v1.y;
            }
        }
#pragma unroll
        for (int j = 0; j < 8; j++) {
            int v = vh * 8 + j;
            float re0 = 0.f, im0 = 0.f, re1 = 0.f, im1 = 0.f;
#pragma unroll
            for (int n = 0; n < 15; n++) {
                float2 c = tw[((n - 7) * v) & 15];
                float2 a0 = ff0[n], a1 = ff1[n];
                re0 += a0.x * c.x - a0.y * c.y;
                im0 += a0.x * c.y + a0.y * c.x;
                re1 += a1.x * c.x - a1.y * c.y;
                im1 += a1.x * c.y + a1.y * c.x;
            }
            g1[0][b * 139 + mm * 17 + v] = make_float2(re0, im0);
            g1[1][b * 139 + mm * 17 + v] = make_float2(re1, im1);
        }
    }
    __syncthreads();
    {   // phase 2: (b, u): Hermitian-paired m-DFT, both zg, real output
        int b = tid & 15, u = tid >> 4;
#pragma unroll
        for (int zz = 0; zz < 2; zz++) {
            int zg = zg0 + zz, g = zg & 31;
            float o[16];
#pragma unroll
            for (int j = 0; j < 16; j++) o[j] = g1[zz][b * 139 + j].x;   // m=0
#pragma unroll
            for (int m = 1; m < 8; m++) {
                float2 c = tw[(m * u) & 15];
#pragma unroll
                for (int j = 0; j < 16; j++) {
                    float2 a = g1[zz][b * 139 + m * 17 + j];
                    o[j] += 2.f * (a.x * c.x - a.y * c.y);
                }
            }
            float bv = bias[g];
            float* ob = out + ((size_t)zg * 16 + b) * 256 + u * 16;
#pragma unroll
            for (int j = 0; j < 16; j += 4)
                *(float4*)&ob[j] = make_float4(o[j] + bv, o[j + 1] + bv,
                                               o[j + 2] + bv, o[j + 3] + bv);
        }
    }
}

extern "C" void kernel_launch(void* const* d_in, const int* in_sizes, int n_in,
                              void* d_out, int out_size, void* d_ws, size_t ws_size,
                              hipStream_t stream) {
    const float* x    = (const float*)d_in[0];
    const float* kern = (const float*)d_in[1];
    const float* bias = (const float*)d_in[2];
    const float* wf   = (const float*)d_in[3];
    const float* wi   = (const float*)d_in[4];
    const float* fre  = (const float*)d_in[5];
    const float* fim  = (const float*)d_in[6];
    float* out = (float*)d_out;

    // workspace layout (bytes):
    // xf2   @0        : 16384*120*8 = 15,728,640
    // xhat  @15728640 : 372*512*8   =  1,523,712
    // yhat  @17252352 : 680*512*8   =  2,785,280
    // zbufT @20037632 : 1024*372*8  =  3,047,424
    // wfT   @23085056 : 372*32*4    =     47,616
    // wiTd  @23132672 : 16384*4     =     65,536
    char* ws = (char*)d_ws;
    float2* xf2   = (float2*)ws;
    float2* xhat  = (float2*)(ws + 15728640);
    float2* yhat  = (float2*)(ws + 17252352);
    float2* zbufT = (float2*)(ws + 20037632);
    float*  wfT   = (float*)(ws + 23085056);
    float*  wiTd  = (float*)(ws + 23132672);

    A12P<<<5567, 256, 0, stream>>>(x, kern, fre, fim, wf, wi, xf2, yhat, wfT, wiTd);
    A3<<<512, 256, 0, stream>>>(xf2, wfT, xhat);
    kD<<<408, 256, 0, stream>>>(xhat, yhat, zbufT);
    kE4<<<512, 256, 0, stream>>>(zbufT, wiTd, bias, out);
}

// Round 21
// 76.527 us; speedup vs baseline: 1.1246x; 1.1246x over previous
//
#include <hip/hip_runtime.h>
#include <math.h>

// SO(3) convolution, B_IN=16, B_OUT=8, BATCH=32, F_IN=16, F_OUT=32.
// Pipeline v20 == v18 (best measured: 76.8/76.9 us; 4 launches):
//   A12P: partial 2D DFT (4 slices/block) + prep tail (yhat, wfT, wiTd);
//         step-2 staged in LDS, coalesced float4 flush.
//   A3  : forward Wigner reduce over b; one block per zf
//   kD  : per-s' complex GEMM (744 x 256, LDS-staged — proven optimum;
//         512-thread / LDS-free / n-paired variants all measured slower)
//   kE4 : dense inverse Wigner + n-DFT + Hermitian m-DFT; two zg per block.

#define NS 680      // full spectral size
#define NR 372      // restricted (m>=0) spectral size
#define NP 24
#define NW 15
#define SLB 4       // slices per A12 block
#define SCALING 0.14433756729740643f  // 1/sqrt(48)

__device__ __constant__ int c_s0[9] = {0, 1, 10, 35, 84, 165, 286, 455, 680};
__device__ __constant__ int c_o[9]  = {0, 1, 7, 22, 50, 95, 161, 252, 372};

// e^{-2pi i k/32}
__device__ __constant__ float2 TW32[32] = {
    { 1.0000000000f,  0.0000000000f}, { 0.9807852804f, -0.1950903220f},
    { 0.9238795325f, -0.3826834324f}, { 0.8314696123f, -0.5555702330f},
    { 0.7071067812f, -0.7071067812f}, { 0.5555702330f, -0.8314696123f},
    { 0.3826834324f, -0.9238795325f}, { 0.1950903220f, -0.9807852804f},
    { 0.0000000000f, -1.0000000000f}, {-0.1950903220f, -0.9807852804f},
    {-0.3826834324f, -0.9238795325f}, {-0.5555702330f, -0.8314696123f},
    {-0.7071067812f, -0.7071067812f}, {-0.8314696123f, -0.5555702330f},
    {-0.9238795325f, -0.3826834324f}, {-0.9807852804f, -0.1950903220f},
    {-1.0000000000f,  0.0000000000f}, {-0.9807852804f,  0.1950903220f},
    {-0.9238795325f,  0.3826834324f}, {-0.8314696123f,  0.5555702330f},
    {-0.7071067812f,  0.7071067812f}, {-0.5555702330f,  0.8314696123f},
    {-0.3826834324f,  0.9238795325f}, {-0.1950903220f,  0.9807852804f},
    { 0.0000000000f,  1.0000000000f}, { 0.1950903220f,  0.9807852804f},
    { 0.3826834324f,  0.9238795325f}, { 0.5555702330f,  0.8314696123f},
    { 0.7071067812f,  0.7071067812f}, { 0.8314696123f,  0.5555702330f},
    { 0.9238795325f,  0.3826834324f}, { 0.9807852804f,  0.1950903220f}};

// e^{+2pi i k/16}
__device__ __constant__ float2 TW16P[16] = {
    { 1.0000000000f,  0.0000000000f}, { 0.9238795325f,  0.3826834324f},
    { 0.7071067812f,  0.7071067812f}, { 0.3826834324f,  0.9238795325f},
    { 0.0000000000f,  1.0000000000f}, {-0.3826834324f,  0.9238795325f},
    {-0.7071067812f,  0.7071067812f}, {-0.9238795325f,  0.3826834324f},
    {-1.0000000000f,  0.0000000000f}, {-0.9238795325f, -0.3826834324f},
    {-0.7071067812f, -0.7071067812f}, {-0.3826834324f, -0.9238795325f},
    { 0.0000000000f, -1.0000000000f}, { 0.3826834324f, -0.9238795325f},
    { 0.7071067812f, -0.7071067812f}, { 0.9238795325f, -0.3826834324f}};

// ---------------- A12P: partial forward DFT + prep tail ---------------------
// grid 5567 = 4096 (A12) + 1471 (prep), block 256.
__global__ __launch_bounds__(256) void A12P(const float* __restrict__ x,
                                            const float* __restrict__ kern,
                                            const float* __restrict__ fre,
                                            const float* __restrict__ fim,
                                            const float* __restrict__ wf,
                                            const float* __restrict__ wi,
                                            float2* __restrict__ xf2,
                                            float2* __restrict__ yhat,
                                            float* __restrict__ wfT,
                                            float* __restrict__ wiTd) {
    __shared__ __align__(16) float  sx[SLB * 1152];   // [sl][u][v] pad 36; reused as xfb
    __shared__ __align__(16) float2 st[SLB][8][34];   // [sl][n][u] pad 34
    __shared__ float2 tw[32];
    int bid = blockIdx.x;
    int tid = threadIdx.x;
    if (bid >= 4096) {   // ---- prep tail (former kP) ----
        int idx = (bid - 4096) * 256 + tid;
        if (idx < NS * 512) {
            int s = idx >> 9, fg = idx & 511;
            float re = 0.f, im = 0.f;
            for (int p = 0; p < NP; p++) {
                float kv = kern[fg * NP + p];
                re += kv * fre[p * NS + s];
                im += kv * fim[p * NS + s];
            }
            yhat[(size_t)s * 512 + fg] = make_float2(re * SCALING, im * SCALING);
            return;
        }
        int j = idx - NS * 512;
        if (j < NR * 32) {
            int sp = j >> 5, b = j & 31;
            int l = 0;
#pragma unroll
            for (int t = 1; t < 8; t++) if (sp >= c_o[t]) l = t;
            int K = 2 * l + 1, r = sp - c_o[l];
            int m = r / K, jn = r - m * K;
            int sf = c_s0[l] + (m + l) * K + jn;
            wfT[sp * 32 + b] = wf[b * NS + sf];
            return;
        }
        int k = j - NR * 32;
        if (k >= 16384) return;
        int ni = k & 15, mm = (k >> 4) & 7, b8 = (k >> 7) & 7;
        int l = (k >> 10) & 7, bh = k >> 13;
        int nn = ni - 7;
        float v = 0.f;
        if (ni < 15 && mm <= l && nn >= -l && nn <= l) {
            int K = 2 * l + 1;
            v = wi[(bh * 8 + b8) * NS + c_s0[l] + (mm + l) * K + (nn + l)];
        }
        wiTd[k] = v;
        return;
    }
    // ---- A12 body ----
    int blk = bid;
    if (tid < 32) tw[tid] = TW32[tid];
    {
        const float4* xs = (const float4*)(x + (size_t)blk * (SLB * 1024));
#pragma unroll
        for (int q = 0; q < SLB; q++) {
            int idx = q * 256 + tid;
            float4 v4 = xs[idx];
            int sl = idx >> 8, w = idx & 255;
            *(float4*)&sx[sl * 1152 + (w >> 3) * 36 + (w & 7) * 4] = v4;
        }
    }
    __syncthreads();
    {   // step 1 (radix-2 over v)
        int u = tid >> 3, n = tid & 7;
        float sgn = (n & 1) ? -1.f : 1.f;
        float2 t8[8];
#pragma unroll
        for (int c = 0; c < 8; c++) t8[c] = tw[(n * c) & 31];
        float2 fa1 = tw[(8 * n) & 31];
#pragma unroll
        for (int sl = 0; sl < SLB; sl++) {
            const float* row = &sx[sl * 1152 + u * 36];
            float4 x0 = *(float4*)&row[0],  x1 = *(float4*)&row[4];
            float4 x2 = *(float4*)&row[8],  x3 = *(float4*)&row[12];
            float4 x4 = *(float4*)&row[16], x5 = *(float4*)&row[20];
            float4 x6 = *(float4*)&row[24], x7 = *(float4*)&row[28];
            float y0  = fmaf(sgn, x4.x, x0.x), y1  = fmaf(sgn, x4.y, x0.y);
            float y2  = fmaf(sgn, x4.z, x0.z), y3  = fmaf(sgn, x4.w, x0.w);
            float y4  = fmaf(sgn, x5.x, x1.x), y5  = fmaf(sgn, x5.y, x1.y);
            float y6  = fmaf(sgn, x5.z, x1.z), y7  = fmaf(sgn, x5.w, x1.w);
            float y8  = fmaf(sgn, x6.x, x2.x), y9  = fmaf(sgn, x6.y, x2.y);
            float y10 = fmaf(sgn, x6.z, x2.z), y11 = fmaf(sgn, x6.w, x2.w);
            float y12 = fmaf(sgn, x7.x, x3.x), y13 = fmaf(sgn, x7.y, x3.y);
            float y14 = fmaf(sgn, x7.z, x3.z), y15 = fmaf(sgn, x7.w, x3.w);
            float p0r = y0 * t8[0].x + y1 * t8[1].x + y2 * t8[2].x + y3 * t8[3].x
                      + y4 * t8[4].x + y5 * t8[5].x + y6 * t8[6].x + y7 * t8[7].x;
            float p0i = y0 * t8[0].y + y1 * t8[1].y + y2 * t8[2].y + y3 * t8[3].y
                      + y4 * t8[4].y + y5 * t8[5].y + y6 * t8[6].y + y7 * t8[7].y;
            float p1r = y8 * t8[0].x + y9 * t8[1].x + y10 * t8[2].x + y11 * t8[3].x
                      + y12 * t8[4].x + y13 * t8[5].x + y14 * t8[6].x + y15 * t8[7].x;
            float p1i = y8 * t8[0].y + y9 * t8[1].y + y10 * t8[2].y + y11 * t8[3].y
                      + y12 * t8[4].y + y13 * t8[5].y + y14 * t8[6].y + y15 * t8[7].y;
            float re = p0r + fa1.x * p1r - fa1.y * p1i;
            float im = p0i + fa1.x * p1i + fa1.y * p1r;
            st[sl][n][u] = make_float2(re, im);
        }
    }
    __syncthreads();
    float2* xfb = (float2*)sx;       // [sl][120] overlay on dead sx region
    {   // step 2: conj-pair outputs -> LDS
        int sl = tid >> 6, m = (tid >> 3) & 7, jj = tid & 7;
        float2 t8[8], fa[4];
#pragma unroll
        for (int c = 0; c < 8; c++) t8[c] = tw[(m * c) & 31];
        fa[0] = make_float2(1.f, 0.f);
#pragma unroll
        for (int a = 1; a < 4; a++) fa[a] = tw[(8 * m * a) & 31];
        float reP = 0.f, imP = 0.f, reN = 0.f, imN = 0.f;
#pragma unroll
        for (int a = 0; a < 4; a++) {
            const float4* spt = (const float4*)&st[sl][jj][a * 8];
            float4 r0 = spt[0], r1 = spt[1], r2 = spt[2], r3 = spt[3];
            float A = r0.x * t8[0].x + r0.z * t8[1].x + r1.x * t8[2].x + r1.z * t8[3].x
                    + r2.x * t8[4].x + r2.z * t8[5].x + r3.x * t8[6].x + r3.z * t8[7].x;
            float B = r0.y * t8[0].y + r0.w * t8[1].y + r1.y * t8[2].y + r1.w * t8[3].y
                    + r2.y * t8[4].y + r2.w * t8[5].y + r3.y * t8[6].y + r3.w * t8[7].y;
            float C = r0.x * t8[0].y + r0.z * t8[1].y + r1.x * t8[2].y + r1.z * t8[3].y
                    + r2.x * t8[4].y + r2.z * t8[5].y + r3.x * t8[6].y + r3.z * t8[7].y;
            float D = r0.y * t8[0].x + r0.w * t8[1].x + r1.y * t8[2].x + r1.w * t8[3].x
                    + r2.y * t8[4].x + r2.w * t8[5].x + r3.y * t8[6].x + r3.w * t8[7].x;
            float prP = A - B, piP = C + D;
            float prN = A + B, piN = C - D;
            reP += fa[a].x * prP - fa[a].y * piP;
            imP += fa[a].x * piP + fa[a].y * prP;
            reN += fa[a].x * prN - fa[a].y * piN;
            imN += fa[a].x * piN + fa[a].y * prN;
        }
        float2* ob = xfb + sl * 120 + m * 15;
        ob[7 + jj] = make_float2(reP, imP);
        if (jj) ob[7 - jj] = make_float2(reN, imN);
    }
    __syncthreads();
    {   // coalesced flush: 480 float2 = 240 float4
        if (tid < 240) {
            float4* dst = (float4*)(xf2 + (size_t)blk * (SLB * 120));
            dst[tid] = ((float4*)xfb)[tid];
        }
    }
}

// ---------------- A3: forward Wigner reduce over b (one block per zf) -------
__global__ __launch_bounds__(256) void A3(const float2* __restrict__ xf2,
                                          const float* __restrict__ wfT,
                                          float2* __restrict__ xhat) {
    __shared__ __align__(16) float2 sxf[32 * 120];
    int zf = blockIdx.x;
    int tid = threadIdx.x;
    {   // float4 staging of contiguous 30 KB tile
        const float4* src = (const float4*)(xf2 + (size_t)zf * (32 * 120));
        float4* dst = (float4*)sxf;
        for (int t = tid; t < 32 * 60; t += 256) dst[t] = src[t];
    }
    __syncthreads();
#pragma unroll
    for (int q = 0; q < 2; q++) {
        if (q == 1 && tid >= NR - 256) break;      // 372 = 256 + 116
        int sp = tid + q * 256;
        int l = 0;
#pragma unroll
        for (int t = 1; t < 8; t++) if (sp >= c_o[t]) l = t;
        int K = 2 * l + 1, r = sp - c_o[l];
        int m = r / K, jn = r - m * K;
        int cell = m * 15 + (jn - l + 7);
        const float4* wp = (const float4*)(wfT + sp * 32);
        const float2* xp = sxf + cell;
        float re = 0.f, im = 0.f;
#pragma unroll
        for (int qq = 0; qq < 8; qq++) {
            float4 w4 = wp[qq];
            float2 v0 = xp[(qq * 4 + 0) * 120];
            float2 v1 = xp[(qq * 4 + 1) * 120];
            float2 v2 = xp[(qq * 4 + 2) * 120];
            float2 v3 = xp[(qq * 4 + 3) * 120];
            re += w4.x * v0.x + w4.y * v1.x + w4.z * v2.x + w4.w * v3.x;
            im += w4.x * v0.y + w4.y * v1.y + w4.z * v2.y + w4.w * v3.y;
        }
        xhat[(size_t)sp * 512 + zf] = make_float2(re, im);
    }
}

// ---------------- kD: per-s' complex GEMM (744 x 256, proven form) ----------
__global__ __launch_bounds__(256) void kD(const float2* __restrict__ xhat,
                                          const float2* __restrict__ yhat,
                                          float2* __restrict__ zbufT) {
    __shared__ __align__(16) float2 Xs[4][16][18];
    __shared__ __align__(16) float2 Ys[4][16][34];
    int sp = 371 - (blockIdx.x >> 1);
    int zh = blockIdx.x & 1;
    int l = 0;
#pragma unroll
    for (int t = 1; t < 8; t++) if (sp >= c_o[t]) l = t;
    int K = 2 * l + 1, r = sp - c_o[l];
    int m = r / K, jn = r - m * K;
    int sX0 = c_o[l] + m * K;
    int sY0 = c_s0[l] + jn * K;
    int tid = threadIdx.x;
    int zl = tid >> 4;
    int g0 = (tid & 15) * 2;
    float2 acc0 = make_float2(0.f, 0.f), acc1 = make_float2(0.f, 0.f);
    int nchunks = (K + 3) >> 2;
    for (int chunk = 0; chunk < nchunks; ++chunk) {
#pragma unroll
        for (int kw = 0; kw < 4; kw++) {
            int k = chunk * 4 + kw;
            if (k < K)
                Xs[kw][tid & 15][tid >> 4] =
                    xhat[(size_t)(sX0 + k) * 512 + (zh * 16 + (tid >> 4)) * 16 + (tid & 15)];
        }
#pragma unroll
        for (int it = 0; it < 8; it++) {
            int kw = it >> 1;
            int fg = (it & 1) * 256 + tid;
            int k = chunk * 4 + kw;
            if (k < K)
                Ys[kw][fg >> 5][fg & 31] = yhat[(size_t)(sY0 + k) * 512 + fg];
        }
        __syncthreads();
#pragma unroll
        for (int kw = 0; kw < 4; kw++) {
            int k = chunk * 4 + kw;
            if (k < K) {
#pragma unroll
                for (int f = 0; f < 16; f++) {
                    float2 xv = Xs[kw][f][zl];
                    float4 y4 = *(const float4*)&Ys[kw][f][g0];
                    acc0.x += xv.x * y4.x + xv.y * y4.y;
                    acc0.y += xv.y * y4.x - xv.x * y4.y;
                    acc1.x += xv.x * y4.z + xv.y * y4.w;
                    acc1.y += xv.y * y4.z - xv.x * y4.w;
                }
            }
        }
        __syncthreads();
    }
    int z0 = zh * 16 + zl;
    zbufT[(size_t)(z0 * 32 + g0) * NR + sp]     = acc0;
    zbufT[(size_t)(z0 * 32 + g0 + 1) * NR + sp] = acc1;
}

// ---------------- kE4: inverse Wigner + inverse 2D DFT, TWO zg per block ----
// grid 512, block 256 = (b, mm, vh); weight loads shared across both zg.
__global__ __launch_bounds__(256) void kE4(const float2* __restrict__ zbufT,
                                           const float* __restrict__ wiTd,
                                           const float* __restrict__ bias,
                                           float* __restrict__ out) {
    __shared__ float2 szp[2][384];        // per-zg padded sz
    __shared__ float2 g1[2][16 * 139];    // per-zg bank-safe g1
    __shared__ float2 tw[16];             // e^{+2pi i k/16}
    int zg0 = blockIdx.x * 2;
    int tid = threadIdx.x;
    if (tid < 16) tw[tid] = TW16P[tid];
    if (tid < 8)    { szp[0][tid] = make_float2(0.f, 0.f);
                      szp[1][tid] = make_float2(0.f, 0.f); }
    if (tid >= 252) { szp[0][tid + 128] = make_float2(0.f, 0.f);
                      szp[1][tid + 128] = make_float2(0.f, 0.f); }
    for (int t = tid; t < NR; t += 256) {
        szp[0][8 + t] = zbufT[(size_t)zg0 * NR + t];
        szp[1][8 + t] = zbufT[(size_t)(zg0 + 1) * NR + t];
    }
    __syncthreads();
    {   // phase 1: (b, mm, vh): dense Wigner rows for BOTH zg + half n-DFT
        int b = tid & 15, mm = (tid >> 4) & 7, vh = tid >> 7;  // vh 0..1
        int bh = b >> 3, b8 = b & 7;
        const int co[8] = {0, 1, 7, 22, 50, 95, 161, 252};
        float2 ff0[15], ff1[15];
#pragma unroll
        for (int n = 0; n < 15; n++) {
            ff0[n] = make_float2(0.f, 0.f);
            ff1[n] = make_float2(0.f, 0.f);
        }
#pragma unroll
        for (int l = 0; l < 8; l++) {
            const float4* wl = (const float4*)(wiTd + ((((bh * 8 + l) * 8 + b8) * 8 + mm) << 4));
            float4 w0 = wl[0], w1 = wl[1], w2 = wl[2], w3 = wl[3];
            float wreg[16] = {w0.x, w0.y, w0.z, w0.w, w1.x, w1.y, w1.z, w1.w,
                              w2.x, w2.y, w2.z, w2.w, w3.x, w3.y, w3.z, w3.w};
            int sp = 1 + co[l] + mm * (2 * l + 1) + l;   // szp index for ni=0
#pragma unroll
            for (int ni = 0; ni < 15; ni++) {
                float w = wreg[ni];
                float2 v0 = szp[0][sp + ni];
                float2 v1 = szp[1][sp + ni];
                ff0[ni].x += w * v0.x; ff0[ni].y += w * v0.y;
                ff1[ni].x += w * v1.x; ff1[ni].y += w * v1.y;
            }
        }
#pragma unroll
        for (int j = 0; j < 8; j++) {
            int v = vh * 8 + j;
            float re0 = 0.f, im0 = 0.f, re1 = 0.f, im1 = 0.f;
#pragma unroll
            for (int n = 0; n < 15; n++) {
                float2 c = tw[((n - 7) * v) & 15];
                float2 a0 = ff0[n], a1 = ff1[n];
                re0 += a0.x * c.x - a0.y * c.y;
                im0 += a0.x * c.y + a0.y * c.x;
                re1 += a1.x * c.x - a1.y * c.y;
                im1 += a1.x * c.y + a1.y * c.x;
            }
            g1[0][b * 139 + mm * 17 + v] = make_float2(re0, im0);
            g1[1][b * 139 + mm * 17 + v] = make_float2(re1, im1);
        }
    }
    __syncthreads();
    {   // phase 2: (b, u): Hermitian-paired m-DFT, both zg, real output
        int b = tid & 15, u = tid >> 4;
#pragma unroll
        for (int zz = 0; zz < 2; zz++) {
            int zg = zg0 + zz, g = zg & 31;
            float o[16];
#pragma unroll
            for (int j = 0; j < 16; j++) o[j] = g1[zz][b * 139 + j].x;   // m=0
#pragma unroll
            for (int m = 1; m < 8; m++) {
                float2 c = tw[(m * u) & 15];
#pragma unroll
                for (int j = 0; j < 16; j++) {
                    float2 a = g1[zz][b * 139 + m * 17 + j];
                    o[j] += 2.f * (a.x * c.x - a.y * c.y);
                }
            }
            float bv = bias[g];
            float* ob = out + ((size_t)zg * 16 + b) * 256 + u * 16;
#pragma unroll
            for (int j = 0; j < 16; j += 4)
                *(float4*)&ob[j] = make_float4(o[j] + bv, o[j + 1] + bv,
                                               o[j + 2] + bv, o[j + 3] + bv);
        }
    }
}

extern "C" void kernel_launch(void* const* d_in, const int* in_sizes, int n_in,
                              void* d_out, int out_size, void* d_ws, size_t ws_size,
                              hipStream_t stream) {
    const float* x    = (const float*)d_in[0];
    const float* kern = (const float*)d_in[1];
    const float* bias = (const float*)d_in[2];
    const float* wf   = (const float*)d_in[3];
    const float* wi   = (const float*)d_in[4];
    const float* fre  = (const float*)d_in[5];
    const float* fim  = (const float*)d_in[6];
    float* out = (float*)d_out;

    // workspace layout (bytes):
    // xf2   @0        : 16384*120*8 = 15,728,640
    // xhat  @15728640 : 372*512*8   =  1,523,712
    // yhat  @17252352 : 680*512*8   =  2,785,280
    // zbufT @20037632 : 1024*372*8  =  3,047,424
    // wfT   @23085056 : 372*32*4    =     47,616
    // wiTd  @23132672 : 16384*4     =     65,536
    char* ws = (char*)d_ws;
    float2* xf2   = (float2*)ws;
    float2* xhat  = (float2*)(ws + 15728640);
    float2* yhat  = (float2*)(ws + 17252352);
    float2* zbufT = (float2*)(ws + 20037632);
    float*  wfT   = (float*)(ws + 23085056);
    float*  wiTd  = (float*)(ws + 23132672);

    A12P<<<5567, 256, 0, stream>>>(x, kern, fre, fim, wf, wi, xf2, yhat, wfT, wiTd);
    A3<<<512, 256, 0, stream>>>(xf2, wfT, xhat);
    kD<<<744, 256, 0, stream>>>(xhat, yhat, zbufT);
    kE4<<<512, 256, 0, stream>>>(zbufT, wiTd, bias, out);
}